// Round 1
// baseline (1225.337 us; speedup 1.0000x reference)
//
#include <hip/hip_runtime.h>

// OnceAggregation (SST VFE): concat -> MLP(128) -> MLP(256) -> {MLP(64) per-point out,
// segment_max -> MLP(256) -> MLP(256) per-voxel out}, out_coors = arange(V) as float.
//
// Strategy R1: bf16 MFMA (16x16x32) with f32 accumulate for all 5 GEMMs, LN+ReLU fused
// in-register per 16-row wave tile, segment_max fused into layer2 epilogue via
// atomicMax on f32-bits (values >= 0 post-ReLU, agg zero-initialized => matches
// where(occ, segment_max, 0)). Weights pre-packed to B-fragment layout (L2-resident).

typedef __attribute__((ext_vector_type(4))) float f32x4;
typedef __attribute__((ext_vector_type(8))) short s16x8;

static constexpr int NP = 500000;
static constexpr int NV = 60000;

__device__ __forceinline__ unsigned short f2bf(float f){
  unsigned int u = __float_as_uint(f);
  u = (u + 0x7FFFu + ((u >> 16) & 1u)) >> 16;   // RNE
  return (unsigned short)u;
}

// Build x0 = bf16(concat(features[125], f_cluster/XYZ_NORM[3]))  [N,128]
__global__ void prep_x0_kernel(const float* __restrict__ feats,
                               const float* __restrict__ fclus,
                               unsigned short* __restrict__ x0, int n){
  int stride = gridDim.x * blockDim.x;
  int total = n * 128;
  for (int i = blockIdx.x * blockDim.x + threadIdx.x; i < total; i += stride){
    int r = i >> 7, k = i & 127;
    float v;
    if (k < 125) v = feats[(size_t)r * 125 + k];
    else         v = fclus[(size_t)r * 3 + (k - 125)] * ((k == 127) ? 0.25f : 0.05f);
    x0[i] = f2bf(v);
  }
}

// Pack W[K][C] (row-major f32) into MFMA-B-fragment order, bf16:
// dst[((n*(K/32)+kc)*64 + lane)*8 + j] = W[kc*32 + (lane>>4)*8 + j][n*16 + (lane&15)]
__global__ void pack_w_kernel(const float* __restrict__ w, unsigned short* __restrict__ dst,
                              int K, int C){
  int total = K * C;
  int stride = gridDim.x * blockDim.x;
  int kc_n = K >> 5;
  for (int i = blockIdx.x * blockDim.x + threadIdx.x; i < total; i += stride){
    int j = i & 7;
    int l = (i >> 3) & 63;
    int rest = i >> 9;
    int kc = rest % kc_n;
    int n  = rest / kc_n;
    int k = kc * 32 + ((l >> 4) << 3) + j;
    int c = (n << 4) + (l & 15);
    dst[i] = f2bf(w[k * C + c]);
  }
}

__global__ void write_coors_kernel(float* __restrict__ o, int v){
  int i = blockIdx.x * blockDim.x + threadIdx.x;
  if (i < v) o[i] = (float)i;
}

// Fused GEMM + bias + LayerNorm + ReLU.  Per wave: 16 rows x C cols.
// A: [M,K] bf16 (or f32 when A_F32, converted in-reg).  Bp: packed bf16 frags.
// OUT_BF16: write bf16 activations to ws; else f32 to d_out.
// DO_ATOMIC: also atomicMax(agg[coors[m]*C + c], f32bits(y)).
template<int K, int C, bool A_F32, bool OUT_BF16, bool DO_ATOMIC>
__global__ __launch_bounds__(256)
void mlp_gemm_kernel(const void* __restrict__ Ain,
                     const unsigned short* __restrict__ Bp,
                     const float* __restrict__ bias,
                     const float* __restrict__ gam,
                     const float* __restrict__ bet,
                     void* __restrict__ Outp, int M,
                     unsigned int* __restrict__ agg,
                     const int* __restrict__ coors){
  constexpr int KC = K / 32;
  constexpr int NT = C / 16;
  const int lane = threadIdx.x & 63;
  const int wave = threadIdx.x >> 6;
  const int m0 = blockIdx.x * 64 + wave * 16;
  if (m0 >= M) return;
  const int col0 = lane & 15;
  const int kgrp = lane >> 4;
  const int arow = m0 + col0;
  const bool arow_ok = arow < M;

  // A fragments: lane holds A[arow][kc*32 + kgrp*8 .. +7]
  s16x8 a[KC];
#pragma unroll
  for (int kc = 0; kc < KC; ++kc){
    if constexpr (A_F32){
      if (arow_ok){
        const float* A = (const float*)Ain;
        const f32x4* p = (const f32x4*)(A + (size_t)arow * K + kc * 32 + kgrp * 8);
        f32x4 u0 = p[0], u1 = p[1];
#pragma unroll
        for (int j = 0; j < 4; ++j){
          a[kc][j]     = (short)f2bf(u0[j]);
          a[kc][j + 4] = (short)f2bf(u1[j]);
        }
      } else {
#pragma unroll
        for (int j = 0; j < 8; ++j) a[kc][j] = 0;
      }
    } else {
      if (arow_ok){
        const unsigned short* A = (const unsigned short*)Ain;
        a[kc] = *(const s16x8*)(A + (size_t)arow * K + kc * 32 + kgrp * 8);
      } else {
#pragma unroll
        for (int j = 0; j < 8; ++j) a[kc][j] = 0;
      }
    }
  }

  // MFMA: D[m][n]: col = lane&15, row = (lane>>4)*4 + reg   [m89-verified]
  f32x4 d[NT];
#pragma unroll
  for (int n = 0; n < NT; ++n){
    f32x4 acc = {0.f, 0.f, 0.f, 0.f};
#pragma unroll
    for (int kc = 0; kc < KC; ++kc){
      s16x8 b = *(const s16x8*)(Bp + ((size_t)(n * KC + kc) * 64 + lane) * 8);
      acc = __builtin_amdgcn_mfma_f32_16x16x32_bf16(a[kc], b, acc, 0, 0, 0);
    }
    d[n] = acc;
  }

  // + bias (before LN, per reference)
#pragma unroll
  for (int n = 0; n < NT; ++n){
    float bv = bias[(n << 4) + col0];
#pragma unroll
    for (int i = 0; i < 4; ++i) d[n][i] += bv;
  }

  // LayerNorm stats per row (rows kgrp*4+i live in the 16 lanes of group kgrp)
  float sum[4] = {0,0,0,0}, sq[4] = {0,0,0,0};
#pragma unroll
  for (int n = 0; n < NT; ++n){
#pragma unroll
    for (int i = 0; i < 4; ++i){ float v = d[n][i]; sum[i] += v; sq[i] += v * v; }
  }
#pragma unroll
  for (int mask = 1; mask < 16; mask <<= 1){
#pragma unroll
    for (int i = 0; i < 4; ++i){
      sum[i] += __shfl_xor(sum[i], mask);
      sq[i]  += __shfl_xor(sq[i],  mask);
    }
  }
  float mean[4], rstd[4];
#pragma unroll
  for (int i = 0; i < 4; ++i){
    float m = sum[i] * (1.f / C);
    float v = sq[i] * (1.f / C) - m * m;
    mean[i] = m;
    rstd[i] = rsqrtf(v + 1e-3f);
  }

  int vox[4];
  if constexpr (DO_ATOMIC){
#pragma unroll
    for (int i = 0; i < 4; ++i){
      int m = m0 + kgrp * 4 + i;
      vox[i] = (m < M) ? coors[m] : 0;
    }
  }

  // epilogue: normalize, scale/shift, relu, store (+ optional segment-max atomics)
#pragma unroll
  for (int n = 0; n < NT; ++n){
    int c = (n << 4) + col0;
    float gv = gam[c], bev = bet[c];
#pragma unroll
    for (int i = 0; i < 4; ++i){
      int m = m0 + kgrp * 4 + i;
      if (m < M){
        float y = (d[n][i] - mean[i]) * rstd[i] * gv + bev;
        y = fmaxf(y, 0.f);
        if constexpr (OUT_BF16) ((unsigned short*)Outp)[(size_t)m * C + c] = f2bf(y);
        else                    ((float*)Outp)[(size_t)m * C + c] = y;
        if constexpr (DO_ATOMIC)
          atomicMax(agg + (size_t)vox[i] * C + c, __float_as_uint(y));
      }
    }
  }
}

extern "C" void kernel_launch(void* const* d_in, const int* in_sizes, int n_in,
                              void* d_out, int out_size, void* d_ws, size_t ws_size,
                              hipStream_t stream){
  const float* features  = (const float*)d_in[1];
  const int*   coors     = (const int*)  d_in[2];
  const float* f_cluster = (const float*)d_in[3];
  const float* w1  = (const float*)d_in[4];
  const float* b1  = (const float*)d_in[5];
  const float* g1  = (const float*)d_in[6];
  const float* be1 = (const float*)d_in[7];
  const float* w2  = (const float*)d_in[8];
  const float* b2  = (const float*)d_in[9];
  const float* g2  = (const float*)d_in[10];
  const float* be2 = (const float*)d_in[11];
  const float* pw1 = (const float*)d_in[12];
  const float* pb1 = (const float*)d_in[13];
  const float* pg1 = (const float*)d_in[14];
  const float* pbe1= (const float*)d_in[15];
  const float* pw2 = (const float*)d_in[16];
  const float* pb2 = (const float*)d_in[17];
  const float* pg2 = (const float*)d_in[18];
  const float* pbe2= (const float*)d_in[19];
  const float* ow  = (const float*)d_in[20];
  const float* ob  = (const float*)d_in[21];
  const float* og  = (const float*)d_in[22];
  const float* obe = (const float*)d_in[23];

  // ws layout (lifetime-aliased; peak ~477.5 MB):
  //  [0, 256M)      : x0 bf16 [N,128] (kernels 3-4) then x2 bf16 [N,256] (kernels 5-6)
  //  [256M, 384M)   : x1 bf16 [N,128]
  //  [384M, 445.4M) : agg f32/u32 [V,256]
  //  [445.4M,476.2M): h bf16 [V,256]
  //  [476.2M, ...)  : packed weights (5 x 256KB slots)
  char* ws = (char*)d_ws;
  unsigned short* x0  = (unsigned short*)(ws + 0);
  unsigned short* x2  = (unsigned short*)(ws + 0);
  unsigned short* x1  = (unsigned short*)(ws + 256000000ull);
  unsigned int*   agg = (unsigned int*)  (ws + 384000000ull);
  unsigned short* h   = (unsigned short*)(ws + 445440000ull);
  unsigned short* w1p = (unsigned short*)(ws + 476160000ull);
  unsigned short* w2p = (unsigned short*)(ws + 476160000ull + 1*262144ull);
  unsigned short* owp = (unsigned short*)(ws + 476160000ull + 2*262144ull);
  unsigned short* pw1p= (unsigned short*)(ws + 476160000ull + 3*262144ull);
  unsigned short* pw2p= (unsigned short*)(ws + 476160000ull + 4*262144ull);

  float* outp      = (float*)d_out;
  float* out_pts   = outp;                       // [N,64]
  float* out_vox   = outp + 32000000;            // [V,256]
  float* out_coors = outp + 47360000;            // [V] (written as float values)

  hipMemsetAsync(agg, 0, (size_t)NV * 256 * 4, stream);

  pack_w_kernel<<<64,  256, 0, stream>>>(w1,  w1p, 128, 128);
  pack_w_kernel<<<128, 256, 0, stream>>>(w2,  w2p, 128, 256);
  pack_w_kernel<<<64,  256, 0, stream>>>(ow,  owp, 256, 64);
  pack_w_kernel<<<256, 256, 0, stream>>>(pw1, pw1p, 256, 256);
  pack_w_kernel<<<256, 256, 0, stream>>>(pw2, pw2p, 256, 256);

  prep_x0_kernel<<<2048, 256, 0, stream>>>(features, f_cluster, x0, NP);

  int gN = (NP + 63) / 64;   // 7813
  int gV = (NV + 63) / 64;   // 938

  // layer1: x0[N,128] -> x1[N,128]
  mlp_gemm_kernel<128,128,false,true ,false><<<gN, 256, 0, stream>>>(
      x0, w1p, b1, g1, be1, x1, NP, nullptr, nullptr);
  // layer2: x1 -> x2[N,256], fused segment-max into agg
  mlp_gemm_kernel<128,256,false,true ,true ><<<gN, 256, 0, stream>>>(
      x1, w2p, b2, g2, be2, x2, NP, agg, coors);
  // out layer: x2 -> out_pts[N,64] (f32, direct to d_out)
  mlp_gemm_kernel<256,64 ,false,false,false><<<gN, 256, 0, stream>>>(
      x2, owp, ob, og, obe, out_pts, NP, nullptr, nullptr);
  // vox layer1: agg(f32) -> h[V,256]
  mlp_gemm_kernel<256,256,true ,true ,false><<<gV, 256, 0, stream>>>(
      (const void*)agg, pw1p, pb1, pg1, pbe1, h, NV, nullptr, nullptr);
  // vox layer2: h -> out_vox[V,256] (f32, direct to d_out)
  mlp_gemm_kernel<256,256,false,false,false><<<gV, 256, 0, stream>>>(
      h, pw2p, pb2, pg2, pbe2, out_vox, NV, nullptr, nullptr);

  write_coors_kernel<<<(NV + 255) / 256, 256, 0, stream>>>(out_coors, NV);
}

// Round 2
// 796.476 us; speedup vs baseline: 1.5384x; 1.5384x over previous
//
#include <hip/hip_runtime.h>

// OnceAggregation R2: sort-based segment-max (no heavy atomics) + fused MLP chains.
//   prep -> [L1 -> LDS -> L2 -> LDS -> out] (one kernel) -> x2, out_pts
//   counting sort by voxel -> gather segment-max (u16 max, exact for relu'd bf16)
//   [pl1 -> LDS -> pl2] (one kernel) -> out_vox ;  out_coors = arange as float.

typedef __attribute__((ext_vector_type(4))) float f32x4;
typedef __attribute__((ext_vector_type(8))) short s16x8;
typedef __attribute__((ext_vector_type(4))) unsigned short u16x4;

static constexpr int NP = 500000;
static constexpr int NV = 60000;
static constexpr int Y1S = 136;   // u16 stride for 16x128 tile (272B = 17*16B, odd -> balanced banks)
static constexpr int Y2S = 280;   // u16 stride for 16x256 tile (560B = 35*16B, odd)

__device__ __forceinline__ unsigned short f2bf(float f){
  unsigned int u = __float_as_uint(f);
  u = (u + 0x7FFFu + ((u >> 16) & 1u)) >> 16;   // RNE
  return (unsigned short)u;
}

// Build x0 = bf16(concat(features[125], f_cluster/XYZ_NORM[3]))  [N,128]
__global__ void prep_x0_kernel(const float* __restrict__ feats,
                               const float* __restrict__ fclus,
                               unsigned short* __restrict__ x0, int n){
  int stride = gridDim.x * blockDim.x;
  int total = n * 128;
  for (int i = blockIdx.x * blockDim.x + threadIdx.x; i < total; i += stride){
    int r = i >> 7, k = i & 127;
    float v;
    if (k < 125) v = feats[(size_t)r * 125 + k];
    else         v = fclus[(size_t)r * 3 + (k - 125)] * ((k == 127) ? 0.25f : 0.05f);
    x0[i] = f2bf(v);
  }
}

// Pack W[K][C] (row-major f32) into MFMA-B-fragment order, bf16:
// dst[((n*(K/32)+kc)*64 + lane)*8 + j] = W[kc*32 + (lane>>4)*8 + j][n*16 + (lane&15)]
__global__ void pack_w_kernel(const float* __restrict__ w, unsigned short* __restrict__ dst,
                              int K, int C){
  int total = K * C;
  int stride = gridDim.x * blockDim.x;
  int kc_n = K >> 5;
  for (int i = blockIdx.x * blockDim.x + threadIdx.x; i < total; i += stride){
    int j = i & 7;
    int l = (i >> 3) & 63;
    int rest = i >> 9;
    int kc = rest % kc_n;
    int n  = rest / kc_n;
    int k = kc * 32 + ((l >> 4) << 3) + j;
    int c = (n << 4) + (l & 15);
    dst[i] = f2bf(w[k * C + c]);
  }
}

__global__ void write_coors_kernel(float* __restrict__ o, int v){
  int i = blockIdx.x * blockDim.x + threadIdx.x;
  if (i < v) o[i] = (float)i;
}

// ---------------- counting sort ----------------
__global__ void hist_kernel(const int* __restrict__ coors, int* __restrict__ counts){
  int stride = gridDim.x * blockDim.x;
  for (int i = blockIdx.x * blockDim.x + threadIdx.x; i < NP; i += stride)
    atomicAdd(&counts[coors[i]], 1);
}

__global__ __launch_bounds__(1024)
void scan_kernel(const int* __restrict__ counts, int* __restrict__ offsets,
                 int* __restrict__ cursor){
  __shared__ int part[1024];
  const int t = threadIdx.x;
  constexpr int PER = (NV + 1023) / 1024;   // 59
  int base = t * PER;
  int s = 0;
  for (int i = 0; i < PER; ++i){ int b = base + i; if (b < NV) s += counts[b]; }
  part[t] = s;
  __syncthreads();
  for (int d = 1; d < 1024; d <<= 1){
    int u = (t >= d) ? part[t - d] : 0;
    __syncthreads();
    part[t] += u;
    __syncthreads();
  }
  int run = (t > 0) ? part[t - 1] : 0;      // exclusive prefix
  for (int i = 0; i < PER; ++i){
    int b = base + i;
    if (b < NV){
      offsets[b] = run; cursor[b] = run;
      run += counts[b];
    }
  }
  if (t == 1023) offsets[NV] = run;         // == NP
}

__global__ void scatter_kernel(const int* __restrict__ coors, int* __restrict__ cursor,
                               int* __restrict__ sorted_idx){
  int stride = gridDim.x * blockDim.x;
  for (int i = blockIdx.x * blockDim.x + threadIdx.x; i < NP; i += stride){
    int v = coors[i];
    int p = atomicAdd(&cursor[v], 1);
    sorted_idx[p] = i;
  }
}

// gather segment-max: one wave per voxel; u16 max is exact (all values relu'd >= 0)
__global__ __launch_bounds__(256)
void segmax_kernel(const unsigned short* __restrict__ x2, const int* __restrict__ offsets,
                   const int* __restrict__ sorted_idx, unsigned short* __restrict__ agg){
  int wid = blockIdx.x * 4 + (threadIdx.x >> 6);
  int lane = threadIdx.x & 63;
  if (wid >= NV) return;
  int beg = offsets[wid], end = offsets[wid + 1];
  unsigned short M0 = 0, M1 = 0, M2 = 0, M3 = 0;
  for (int p = beg; p < end; ++p){
    int idx = sorted_idx[p];
    u16x4 v = *(const u16x4*)(x2 + (size_t)idx * 256 + lane * 4);
    M0 = max(M0, v[0]); M1 = max(M1, v[1]); M2 = max(M2, v[2]); M3 = max(M3, v[3]);
  }
  u16x4 o = {M0, M1, M2, M3};
  *(u16x4*)(agg + (size_t)wid * 256 + lane * 4) = o;
}

// ---------------- fused MLP helpers ----------------
template<int KC, int NT>
__device__ __forceinline__ void gemm_frags(const s16x8* a, const unsigned short* __restrict__ Bp,
                                           int lane, f32x4* d){
#pragma unroll
  for (int n = 0; n < NT; ++n){
    f32x4 acc = {0.f, 0.f, 0.f, 0.f};
#pragma unroll
    for (int kc = 0; kc < KC; ++kc){
      s16x8 b = *(const s16x8*)(Bp + ((size_t)(n * KC + kc) * 64 + lane) * 8);
      acc = __builtin_amdgcn_mfma_f32_16x16x32_bf16(a[kc], b, acc, 0, 0, 0);
    }
    d[n] = acc;
  }
}

template<int NT, int C>
__device__ __forceinline__ void bias_ln_relu(f32x4* d, const float* __restrict__ bias,
                                             const float* __restrict__ gam,
                                             const float* __restrict__ bet, int col0){
  float sum[4] = {0,0,0,0}, sq[4] = {0,0,0,0};
#pragma unroll
  for (int n = 0; n < NT; ++n){
    float bv = bias[n * 16 + col0];
#pragma unroll
    for (int i = 0; i < 4; ++i){
      float v = d[n][i] + bv; d[n][i] = v;
      sum[i] += v; sq[i] += v * v;
    }
  }
#pragma unroll
  for (int mask = 1; mask < 16; mask <<= 1){
#pragma unroll
    for (int i = 0; i < 4; ++i){
      sum[i] += __shfl_xor(sum[i], mask);
      sq[i]  += __shfl_xor(sq[i],  mask);
    }
  }
#pragma unroll
  for (int i = 0; i < 4; ++i){
    float m = sum[i] * (1.f / C);
    float var = sq[i] * (1.f / C) - m * m;
    sum[i] = m;
    sq[i]  = rsqrtf(var + 1e-3f);
  }
#pragma unroll
  for (int n = 0; n < NT; ++n){
    float gv = gam[n * 16 + col0], bv = bet[n * 16 + col0];
#pragma unroll
    for (int i = 0; i < 4; ++i){
      float y = (d[n][i] - sum[i]) * sq[i] * gv + bv;
      d[n][i] = fmaxf(y, 0.f);
    }
  }
}

template<int NT, int STRIDE>
__device__ __forceinline__ void store_tile_lds(unsigned short* my, const f32x4* d,
                                               int l15, int kg){
#pragma unroll
  for (int n = 0; n < NT; ++n){
    int c = n * 16 + l15;
#pragma unroll
    for (int i = 0; i < 4; ++i)
      my[(kg * 4 + i) * STRIDE + c] = f2bf(d[n][i]);
  }
}

template<int KC, int STRIDE>
__device__ __forceinline__ void load_afrags_lds(const unsigned short* my, int l15, int kg,
                                                s16x8* a){
#pragma unroll
  for (int kc = 0; kc < KC; ++kc)
    a[kc] = *(const s16x8*)&my[l15 * STRIDE + kc * 32 + kg * 8];
}

// ---------------- fused point pipeline: x0 -> L1 -> L2 -> out ----------------
__global__ __launch_bounds__(256)
void point_fused_kernel(const unsigned short* __restrict__ x0,
                        const unsigned short* __restrict__ w1p,
                        const unsigned short* __restrict__ w2p,
                        const unsigned short* __restrict__ owp,
                        const float* __restrict__ b1, const float* __restrict__ g1,
                        const float* __restrict__ be1,
                        const float* __restrict__ b2, const float* __restrict__ g2,
                        const float* __restrict__ be2,
                        const float* __restrict__ ob, const float* __restrict__ og,
                        const float* __restrict__ obe,
                        unsigned short* __restrict__ x2,
                        float* __restrict__ out_pts){
  __shared__ __align__(16) unsigned short lds[4][16 * Y2S];
  const int lane = threadIdx.x & 63;
  const int wave = threadIdx.x >> 6;
  const int m0 = blockIdx.x * 64 + wave * 16;
  if (m0 >= NP) return;
  unsigned short* my = lds[wave];
  const int l15 = lane & 15, kg = lane >> 4;
  const int arow = m0 + l15;
  const bool aok = arow < NP;

  // layer1: y1 = LN_relu(x0 @ w1 + b1)   [16,128]
  s16x8 a1[4];
#pragma unroll
  for (int kc = 0; kc < 4; ++kc){
    if (aok) a1[kc] = *(const s16x8*)(x0 + (size_t)arow * 128 + kc * 32 + kg * 8);
    else {
#pragma unroll
      for (int j = 0; j < 8; ++j) a1[kc][j] = 0;
    }
  }
  f32x4 d1[8];
  gemm_frags<4, 8>(a1, w1p, lane, d1);
  bias_ln_relu<8, 128>(d1, b1, g1, be1, l15);
  store_tile_lds<8, Y1S>(my, d1, l15, kg);

  // layer2: y2 = LN_relu(y1 @ w2 + b2)   [16,256]
  s16x8 a2[4];
  load_afrags_lds<4, Y1S>(my, l15, kg, a2);
  f32x4 d2[16];
  gemm_frags<4, 16>(a2, w2p, lane, d2);
  bias_ln_relu<16, 256>(d2, b2, g2, be2, l15);
  store_tile_lds<16, Y2S>(my, d2, l15, kg);

  // x2 store via coalesced LDS readback (col-block = 4k+chunk balances banks)
  {
    const int r = l15, ch = kg;   // 16 rows x 4 chunks
#pragma unroll
    for (int k = 0; k < 8; ++k){
      int cb = 4 * k + ch;        // 0..31, 8 cols each
      s16x8 v = *(const s16x8*)&my[r * Y2S + cb * 8];
      if (m0 + r < NP)
        *(s16x8*)(x2 + (size_t)(m0 + r) * 256 + cb * 8) = v;
    }
  }

  // out layer: out = LN_relu(y2 @ ow + ob)   [16,64] f32 -> d_out
  s16x8 a3[8];
  load_afrags_lds<8, Y2S>(my, l15, kg, a3);
  f32x4 d3[4];
  gemm_frags<8, 4>(a3, owp, lane, d3);
  bias_ln_relu<4, 64>(d3, ob, og, obe, l15);
#pragma unroll
  for (int n = 0; n < 4; ++n){
    int c = n * 16 + l15;
#pragma unroll
    for (int i = 0; i < 4; ++i){
      int m = m0 + kg * 4 + i;
      if (m < NP) out_pts[(size_t)m * 64 + c] = d3[n][i];
    }
  }
}

// ---------------- fused voxel pipeline: agg -> pl1 -> pl2 -> out_vox ----------------
__global__ __launch_bounds__(256)
void vox_fused_kernel(const unsigned short* __restrict__ agg,
                      const unsigned short* __restrict__ pw1p,
                      const unsigned short* __restrict__ pw2p,
                      const float* __restrict__ pb1, const float* __restrict__ pg1,
                      const float* __restrict__ pbe1,
                      const float* __restrict__ pb2, const float* __restrict__ pg2,
                      const float* __restrict__ pbe2,
                      float* __restrict__ out_vox){
  __shared__ __align__(16) unsigned short lds[4][16 * Y2S];
  const int lane = threadIdx.x & 63;
  const int wave = threadIdx.x >> 6;
  const int m0 = blockIdx.x * 64 + wave * 16;
  if (m0 >= NV) return;
  unsigned short* my = lds[wave];
  const int l15 = lane & 15, kg = lane >> 4;
  const int arow = m0 + l15;
  const bool aok = arow < NV;

  s16x8 a[8];
#pragma unroll
  for (int kc = 0; kc < 8; ++kc){
    if (aok) a[kc] = *(const s16x8*)(agg + (size_t)arow * 256 + kc * 32 + kg * 8);
    else {
#pragma unroll
      for (int j = 0; j < 8; ++j) a[kc][j] = 0;
    }
  }
  f32x4 d[16];
  gemm_frags<8, 16>(a, pw1p, lane, d);
  bias_ln_relu<16, 256>(d, pb1, pg1, pbe1, l15);
  store_tile_lds<16, Y2S>(my, d, l15, kg);

  s16x8 a2[8];
  load_afrags_lds<8, Y2S>(my, l15, kg, a2);
  gemm_frags<8, 16>(a2, pw2p, lane, d);
  bias_ln_relu<16, 256>(d, pb2, pg2, pbe2, l15);
#pragma unroll
  for (int n = 0; n < 16; ++n){
    int c = n * 16 + l15;
#pragma unroll
    for (int i = 0; i < 4; ++i){
      int m = m0 + kg * 4 + i;
      if (m < NV) out_vox[(size_t)m * 256 + c] = d[n][i];
    }
  }
}

extern "C" void kernel_launch(void* const* d_in, const int* in_sizes, int n_in,
                              void* d_out, int out_size, void* d_ws, size_t ws_size,
                              hipStream_t stream){
  const float* features  = (const float*)d_in[1];
  const int*   coors     = (const int*)  d_in[2];
  const float* f_cluster = (const float*)d_in[3];
  const float* w1  = (const float*)d_in[4];
  const float* b1  = (const float*)d_in[5];
  const float* g1  = (const float*)d_in[6];
  const float* be1 = (const float*)d_in[7];
  const float* w2  = (const float*)d_in[8];
  const float* b2  = (const float*)d_in[9];
  const float* g2  = (const float*)d_in[10];
  const float* be2 = (const float*)d_in[11];
  const float* pw1 = (const float*)d_in[12];
  const float* pb1 = (const float*)d_in[13];
  const float* pg1 = (const float*)d_in[14];
  const float* pbe1= (const float*)d_in[15];
  const float* pw2 = (const float*)d_in[16];
  const float* pb2 = (const float*)d_in[17];
  const float* pg2 = (const float*)d_in[18];
  const float* pbe2= (const float*)d_in[19];
  const float* ow  = (const float*)d_in[20];
  const float* ob  = (const float*)d_in[21];
  const float* og  = (const float*)d_in[22];
  const float* obe = (const float*)d_in[23];

  char* ws = (char*)d_ws;
  unsigned short* x0   = (unsigned short*)(ws + 0);
  unsigned short* x2   = (unsigned short*)(ws + 128000000ull);
  unsigned short* aggb = (unsigned short*)(ws + 384000000ull);
  int* counts   = (int*)(ws + 414720000ull);
  int* offsets  = (int*)(ws + 414961024ull);
  int* cursor   = (int*)(ws + 415202048ull);
  int* sidx     = (int*)(ws + 415443072ull);
  unsigned short* w1p = (unsigned short*)(ws + 417443072ull);
  unsigned short* w2p = (unsigned short*)(ws + 417443072ull + 1*262144ull);
  unsigned short* owp = (unsigned short*)(ws + 417443072ull + 2*262144ull);
  unsigned short* pw1p= (unsigned short*)(ws + 417443072ull + 3*262144ull);
  unsigned short* pw2p= (unsigned short*)(ws + 417443072ull + 4*262144ull);

  float* outp      = (float*)d_out;
  float* out_pts   = outp;                       // [N,64]
  float* out_vox   = outp + 32000000;            // [V,256]
  float* out_coors = outp + 47360000;            // [V] as float

  hipMemsetAsync(counts, 0, (size_t)(NV + 1) * sizeof(int), stream);

  pack_w_kernel<<<64,  256, 0, stream>>>(w1,  w1p, 128, 128);
  pack_w_kernel<<<128, 256, 0, stream>>>(w2,  w2p, 128, 256);
  pack_w_kernel<<<64,  256, 0, stream>>>(ow,  owp, 256, 64);
  pack_w_kernel<<<256, 256, 0, stream>>>(pw1, pw1p, 256, 256);
  pack_w_kernel<<<256, 256, 0, stream>>>(pw2, pw2p, 256, 256);

  prep_x0_kernel<<<2048, 256, 0, stream>>>(features, f_cluster, x0, NP);

  hist_kernel<<<2048, 256, 0, stream>>>(coors, counts);
  scan_kernel<<<1, 1024, 0, stream>>>(counts, offsets, cursor);
  scatter_kernel<<<2048, 256, 0, stream>>>(coors, cursor, sidx);

  point_fused_kernel<<<(NP + 63) / 64, 256, 0, stream>>>(
      x0, w1p, w2p, owp, b1, g1, be1, b2, g2, be2, ob, og, obe, x2, out_pts);

  segmax_kernel<<<NV / 4, 256, 0, stream>>>(x2, offsets, sidx, aggb);

  vox_fused_kernel<<<(NV + 63) / 64, 256, 0, stream>>>(
      aggb, pw1p, pw2p, pb1, pg1, pbe1, pb2, pg2, pbe2, out_vox);

  write_coors_kernel<<<(NV + 255) / 256, 256, 0, stream>>>(out_coors, NV);
}

// Round 3
// 779.099 us; speedup vs baseline: 1.5728x; 1.0223x over previous
//
#include <hip/hip_runtime.h>

// OnceAggregation R3: swapped-operand MFMA (y^T = W^T @ x^T) + permuted weight packs
// so inter-layer fragment conversion is pure in-register (no LDS, no shuffles).
// Pipeline: [pack_all + coors] ; [prep x0 + hist] ; scan ; scatter ;
//           point_fused (L1->L2->out, writes x2 permuted) ; segmax (sorted gather) ;
//           vox_fused (pl1->pl2).  Feature order of x2/agg is permuted by
//           pi(s)= (s&~31) | ((j>>2)<<4) | (g<<2) | (j&3); all downstream packs use pi.

typedef __attribute__((ext_vector_type(4))) float f32x4;
typedef __attribute__((ext_vector_type(8))) short s16x8;
typedef __attribute__((ext_vector_type(4))) unsigned short u16x4;

static constexpr int NP = 500000;   // 32 | NP  -> no tail guards inside waves
static constexpr int NV = 60000;    // 32 | NV

__device__ __forceinline__ unsigned short f2bf(float f){
  unsigned int u = __float_as_uint(f);
  u = (u + 0x7FFFu + ((u >> 16) & 1u)) >> 16;   // RNE
  return (unsigned short)u;
}

// ---------------- combined small-work kernel: 5 weight packs + out_coors ----------------
// A-fragment pack for swapped GEMM: lane l holds W[k][n*16 + (l&15)] for k-slots
// kc*32 + g*8 + j ; with perm, k_orig = kc*32 + ((j>>2)<<4) + g*4 + (j&3).
__device__ __forceinline__ void pack_one(const float* __restrict__ w,
                                         unsigned short* __restrict__ dst,
                                         int K, int C, bool perm, int idx){
  int j = idx & 7, l = (idx >> 3) & 63, rest = idx >> 9;
  int kcn = K >> 5;
  int kc = rest % kcn, n = rest / kcn;
  int g = l >> 4, t = l & 15;
  int k = perm ? (kc * 32 + ((j >> 2) << 4) + g * 4 + (j & 3))
               : (kc * 32 + g * 8 + j);
  dst[idx] = f2bf(w[(size_t)k * C + n * 16 + t]);
}

__global__ void pack_all_kernel(const float* __restrict__ w1, const float* __restrict__ w2,
                                const float* __restrict__ ow, const float* __restrict__ pw1,
                                const float* __restrict__ pw2,
                                unsigned short* __restrict__ w1p, unsigned short* __restrict__ w2p,
                                unsigned short* __restrict__ owp, unsigned short* __restrict__ pw1p,
                                unsigned short* __restrict__ pw2p,
                                float* __restrict__ out_coors){
  int stride = gridDim.x * blockDim.x;
  const int T = 196608 + NV;
  for (int i = blockIdx.x * blockDim.x + threadIdx.x; i < T; i += stride){
    if      (i < 16384)  pack_one(w1,  w1p,  128, 128, false, i);
    else if (i < 49152)  pack_one(w2,  w2p,  128, 256, true,  i - 16384);
    else if (i < 65536)  pack_one(ow,  owp,  256, 64,  true,  i - 49152);
    else if (i < 131072) pack_one(pw1, pw1p, 256, 256, true,  i - 65536);
    else if (i < 196608) pack_one(pw2, pw2p, 256, 256, true,  i - 131072);
    else                 out_coors[i - 196608] = (float)(i - 196608);
  }
}

// ---------------- prep x0 (vectorized) + histogram ----------------
__global__ void prep_hist_kernel(const float* __restrict__ feats,
                                 const float* __restrict__ fclus,
                                 const int* __restrict__ coors,
                                 unsigned short* __restrict__ x0,
                                 int* __restrict__ counts){
  int stride = gridDim.x * blockDim.x;
  int tid = blockIdx.x * blockDim.x + threadIdx.x;
  for (int i = tid; i < NP * 16; i += stride){
    int r = i >> 4, cb = i & 15;
    const float* frow = feats + (size_t)r * 125;
    s16x8 v;
#pragma unroll
    for (int j = 0; j < 8; ++j){
      int c = cb * 8 + j;
      float f = (c < 125) ? frow[c]
                          : fclus[(size_t)r * 3 + (c - 125)] * ((c == 127) ? 0.25f : 0.05f);
      v[j] = (short)f2bf(f);
    }
    *(s16x8*)(x0 + (size_t)r * 128 + cb * 8) = v;
  }
  for (int i = tid; i < NP; i += stride)
    atomicAdd(&counts[coors[i]], 1);
}

// ---------------- counting sort (scan + scatter) ----------------
__global__ __launch_bounds__(1024)
void scan_kernel(const int* __restrict__ counts, int* __restrict__ offsets,
                 int* __restrict__ cursor){
  __shared__ int part[1024];
  const int t = threadIdx.x;
  constexpr int PER = (NV + 1023) / 1024;
  int base = t * PER;
  int s = 0;
  for (int i = 0; i < PER; ++i){ int b = base + i; if (b < NV) s += counts[b]; }
  part[t] = s;
  __syncthreads();
  for (int d = 1; d < 1024; d <<= 1){
    int u = (t >= d) ? part[t - d] : 0;
    __syncthreads();
    part[t] += u;
    __syncthreads();
  }
  int run = (t > 0) ? part[t - 1] : 0;
  for (int i = 0; i < PER; ++i){
    int b = base + i;
    if (b < NV){ offsets[b] = run; cursor[b] = run; run += counts[b]; }
  }
  if (t == 1023) offsets[NV] = run;
}

__global__ void scatter_kernel(const int* __restrict__ coors, int* __restrict__ cursor,
                               int* __restrict__ sorted_idx){
  int stride = gridDim.x * blockDim.x;
  for (int i = blockIdx.x * blockDim.x + threadIdx.x; i < NP; i += stride){
    int v = coors[i];
    int p = atomicAdd(&cursor[v], 1);
    sorted_idx[p] = i;
  }
}

// gather segment-max (u16 max exact for relu'd bf16 >= 0); empty voxels stay 0.
__global__ __launch_bounds__(256)
void segmax_kernel(const unsigned short* __restrict__ x2, const int* __restrict__ offsets,
                   const int* __restrict__ sorted_idx, unsigned short* __restrict__ agg){
  int wid = blockIdx.x * 4 + (threadIdx.x >> 6);
  int lane = threadIdx.x & 63;
  if (wid >= NV) return;
  int beg = offsets[wid], end = offsets[wid + 1];
  unsigned short M0 = 0, M1 = 0, M2 = 0, M3 = 0;
  for (int p = beg; p < end; ++p){
    int idx = sorted_idx[p];
    u16x4 v = *(const u16x4*)(x2 + (size_t)idx * 256 + lane * 4);
    M0 = max(M0, v[0]); M1 = max(M1, v[1]); M2 = max(M2, v[2]); M3 = max(M3, v[3]);
  }
  u16x4 o = {M0, M1, M2, M3};
  *(u16x4*)(agg + (size_t)wid * 256 + lane * 4) = o;
}

// ---------------- swapped-GEMM building blocks ----------------
// D = Wfrag (A) x actfrag (B): point = lane&15, outfeature = n*16 + (lane>>4)*4 + i.
template<int KC, int NT>
__device__ __forceinline__ void gemm2x(const s16x8* bA, const s16x8* bB,
                                       const unsigned short* __restrict__ Wp,
                                       int lane, f32x4* dA, f32x4* dB){
#pragma unroll
  for (int n = 0; n < NT; ++n){
    f32x4 aA = {0.f,0.f,0.f,0.f}, aB = {0.f,0.f,0.f,0.f};
#pragma unroll
    for (int kc = 0; kc < KC; ++kc){
      s16x8 w = *(const s16x8*)(Wp + ((size_t)(n * KC + kc) * 64 + lane) * 8);
      aA = __builtin_amdgcn_mfma_f32_16x16x32_bf16(w, bA[kc], aA, 0, 0, 0);
      aB = __builtin_amdgcn_mfma_f32_16x16x32_bf16(w, bB[kc], aB, 0, 0, 0);
    }
    dA[n] = aA; dB[n] = aB;
  }
}

// bias + LayerNorm + ReLU in swapped layout: features live across (n, i, lane-group g);
// per-point reduce = in-lane sums + shfl_xor over lane groups (16, 32).
template<int NT, int C>
__device__ __forceinline__ void bias_ln_relu_sw(f32x4* d0, f32x4* d1,
                                                const float* __restrict__ bias,
                                                const float* __restrict__ gam,
                                                const float* __restrict__ bet, int g){
  float s0 = 0.f, s1 = 0.f, q0 = 0.f, q1 = 0.f;
#pragma unroll
  for (int n = 0; n < NT; ++n){
    f32x4 bv = *(const f32x4*)(bias + n * 16 + g * 4);
#pragma unroll
    for (int i = 0; i < 4; ++i){
      float v0 = d0[n][i] + bv[i]; d0[n][i] = v0; s0 += v0; q0 += v0 * v0;
      float v1 = d1[n][i] + bv[i]; d1[n][i] = v1; s1 += v1; q1 += v1 * v1;
    }
  }
  s0 += __shfl_xor(s0, 16); s0 += __shfl_xor(s0, 32);
  q0 += __shfl_xor(q0, 16); q0 += __shfl_xor(q0, 32);
  s1 += __shfl_xor(s1, 16); s1 += __shfl_xor(s1, 32);
  q1 += __shfl_xor(q1, 16); q1 += __shfl_xor(q1, 32);
  float m0 = s0 * (1.f / C), m1 = s1 * (1.f / C);
  float r0 = rsqrtf(q0 * (1.f / C) - m0 * m0 + 1e-3f);
  float r1 = rsqrtf(q1 * (1.f / C) - m1 * m1 + 1e-3f);
#pragma unroll
  for (int n = 0; n < NT; ++n){
    f32x4 gv  = *(const f32x4*)(gam + n * 16 + g * 4);
    f32x4 bev = *(const f32x4*)(bet + n * 16 + g * 4);
#pragma unroll
    for (int i = 0; i < 4; ++i){
      d0[n][i] = fmaxf((d0[n][i] - m0) * r0 * gv[i] + bev[i], 0.f);
      d1[n][i] = fmaxf((d1[n][i] - m1) * r1 * gv[i] + bev[i], 0.f);
    }
  }
}

// In-register fragment conversion: next-layer B frag[kc] = bf16{d[2kc][0..3], d[2kc+1][0..3]}
// (valid because the next weight pack uses permutation pi).
template<int NT>
__device__ __forceinline__ void to_frags(const f32x4* d, s16x8* f){
#pragma unroll
  for (int kc = 0; kc < NT / 2; ++kc){
#pragma unroll
    for (int u = 0; u < 4; ++u) f[kc][u]     = (short)f2bf(d[2 * kc][u]);
#pragma unroll
    for (int u = 0; u < 4; ++u) f[kc][4 + u] = (short)f2bf(d[2 * kc + 1][u]);
  }
}

// ---------------- fused point pipeline: x0 -> L1 -> L2 -> {x2 (permuted), out layer} ----------------
__global__ __launch_bounds__(256, 2)
void point_fused_kernel(const unsigned short* __restrict__ x0,
                        const unsigned short* __restrict__ w1p,
                        const unsigned short* __restrict__ w2p,
                        const unsigned short* __restrict__ owp,
                        const float* __restrict__ b1, const float* __restrict__ g1,
                        const float* __restrict__ be1,
                        const float* __restrict__ b2, const float* __restrict__ g2,
                        const float* __restrict__ be2,
                        const float* __restrict__ ob, const float* __restrict__ og,
                        const float* __restrict__ obe,
                        unsigned short* __restrict__ x2,
                        float* __restrict__ out_pts){
  const int lane = threadIdx.x & 63;
  const int wave = threadIdx.x >> 6;
  const int m0 = blockIdx.x * 128 + wave * 32;   // 32 points per wave (NP % 32 == 0)
  if (m0 >= NP) return;
  const int g = lane >> 4, t = lane & 15;
  const size_t mA = m0 + t, mB = m0 + 16 + t;

  // layer1 B frags straight from x0 (identity k-order)
  s16x8 bfA[4], bfB[4];
#pragma unroll
  for (int kc = 0; kc < 4; ++kc){
    bfA[kc] = *(const s16x8*)(x0 + mA * 128 + kc * 32 + g * 8);
    bfB[kc] = *(const s16x8*)(x0 + mB * 128 + kc * 32 + g * 8);
  }
  f32x4 d1a[8], d1b[8];
  gemm2x<4, 8>(bfA, bfB, w1p, lane, d1a, d1b);
  bias_ln_relu_sw<8, 128>(d1a, d1b, b1, g1, be1, g);

  s16x8 f2a[4], f2b[4];
  to_frags<8>(d1a, f2a); to_frags<8>(d1b, f2b);

  f32x4 d2a[16], d2b[16];
  gemm2x<4, 16>(f2a, f2b, w2p, lane, d2a, d2b);
  bias_ln_relu_sw<16, 256>(d2a, d2b, b2, g2, be2, g);

  s16x8 f3a[8], f3b[8];
  to_frags<16>(d2a, f3a); to_frags<16>(d2b, f3b);

  // x2 store (permuted feature order; segmax/vox packs compensate)
#pragma unroll
  for (int kc = 0; kc < 8; ++kc){
    *(s16x8*)(x2 + mA * 256 + kc * 32 + g * 8) = f3a[kc];
    *(s16x8*)(x2 + mB * 256 + kc * 32 + g * 8) = f3b[kc];
  }

  f32x4 d3a[4], d3b[4];
  gemm2x<8, 4>(f3a, f3b, owp, lane, d3a, d3b);
  bias_ln_relu_sw<4, 64>(d3a, d3b, ob, og, obe, g);
#pragma unroll
  for (int n = 0; n < 4; ++n){
    *(f32x4*)(out_pts + mA * 64 + n * 16 + g * 4) = d3a[n];
    *(f32x4*)(out_pts + mB * 64 + n * 16 + g * 4) = d3b[n];
  }
}

// ---------------- fused voxel pipeline: agg(permuted) -> pl1 -> pl2 -> out_vox ----------------
__global__ __launch_bounds__(256, 2)
void vox_fused_kernel(const unsigned short* __restrict__ agg,
                      const unsigned short* __restrict__ pw1p,
                      const unsigned short* __restrict__ pw2p,
                      const float* __restrict__ pb1, const float* __restrict__ pg1,
                      const float* __restrict__ pbe1,
                      const float* __restrict__ pb2, const float* __restrict__ pg2,
                      const float* __restrict__ pbe2,
                      float* __restrict__ out_vox){
  const int lane = threadIdx.x & 63;
  const int wave = threadIdx.x >> 6;
  const int m0 = blockIdx.x * 128 + wave * 32;   // NV % 32 == 0
  if (m0 >= NV) return;
  const int g = lane >> 4, t = lane & 15;
  const size_t mA = m0 + t, mB = m0 + 16 + t;

  s16x8 bfA[8], bfB[8];
#pragma unroll
  for (int kc = 0; kc < 8; ++kc){
    bfA[kc] = *(const s16x8*)(agg + mA * 256 + kc * 32 + g * 8);
    bfB[kc] = *(const s16x8*)(agg + mB * 256 + kc * 32 + g * 8);
  }
  f32x4 da[16], db[16];
  gemm2x<8, 16>(bfA, bfB, pw1p, lane, da, db);
  bias_ln_relu_sw<16, 256>(da, db, pb1, pg1, pbe1, g);

  s16x8 fa[8], fb[8];
  to_frags<16>(da, fa); to_frags<16>(db, fb);

  gemm2x<8, 16>(fa, fb, pw2p, lane, da, db);
  bias_ln_relu_sw<16, 256>(da, db, pb2, pg2, pbe2, g);
#pragma unroll
  for (int n = 0; n < 16; ++n){
    *(f32x4*)(out_vox + mA * 256 + n * 16 + g * 4) = da[n];
    *(f32x4*)(out_vox + mB * 256 + n * 16 + g * 4) = db[n];
  }
}

extern "C" void kernel_launch(void* const* d_in, const int* in_sizes, int n_in,
                              void* d_out, int out_size, void* d_ws, size_t ws_size,
                              hipStream_t stream){
  const float* features  = (const float*)d_in[1];
  const int*   coors     = (const int*)  d_in[2];
  const float* f_cluster = (const float*)d_in[3];
  const float* w1  = (const float*)d_in[4];
  const float* b1  = (const float*)d_in[5];
  const float* g1  = (const float*)d_in[6];
  const float* be1 = (const float*)d_in[7];
  const float* w2  = (const float*)d_in[8];
  const float* b2  = (const float*)d_in[9];
  const float* g2  = (const float*)d_in[10];
  const float* be2 = (const float*)d_in[11];
  const float* pw1 = (const float*)d_in[12];
  const float* pb1 = (const float*)d_in[13];
  const float* pg1 = (const float*)d_in[14];
  const float* pbe1= (const float*)d_in[15];
  const float* pw2 = (const float*)d_in[16];
  const float* pb2 = (const float*)d_in[17];
  const float* pg2 = (const float*)d_in[18];
  const float* pbe2= (const float*)d_in[19];
  const float* ow  = (const float*)d_in[20];
  const float* ob  = (const float*)d_in[21];
  const float* og  = (const float*)d_in[22];
  const float* obe = (const float*)d_in[23];

  char* ws = (char*)d_ws;
  unsigned short* x0   = (unsigned short*)(ws + 0);
  unsigned short* x2   = (unsigned short*)(ws + 128000000ull);
  unsigned short* aggb = (unsigned short*)(ws + 384000000ull);
  int* counts   = (int*)(ws + 414720000ull);
  int* offsets  = (int*)(ws + 414961024ull);
  int* cursor   = (int*)(ws + 415202048ull);
  int* sidx     = (int*)(ws + 415443072ull);
  unsigned short* w1p = (unsigned short*)(ws + 417443072ull);
  unsigned short* w2p = (unsigned short*)(ws + 417443072ull + 1*262144ull);
  unsigned short* owp = (unsigned short*)(ws + 417443072ull + 2*262144ull);
  unsigned short* pw1p= (unsigned short*)(ws + 417443072ull + 3*262144ull);
  unsigned short* pw2p= (unsigned short*)(ws + 417443072ull + 4*262144ull);

  float* outp      = (float*)d_out;
  float* out_pts   = outp;                       // [N,64]
  float* out_vox   = outp + 32000000;            // [V,256]
  float* out_coors = outp + 47360000;            // [V] as float

  hipMemsetAsync(counts, 0, (size_t)(NV + 1) * sizeof(int), stream);

  pack_all_kernel<<<512, 256, 0, stream>>>(w1, w2, ow, pw1, pw2,
                                           w1p, w2p, owp, pw1p, pw2p, out_coors);

  prep_hist_kernel<<<2048, 256, 0, stream>>>(features, f_cluster, coors, x0, counts);

  scan_kernel<<<1, 1024, 0, stream>>>(counts, offsets, cursor);
  scatter_kernel<<<2048, 256, 0, stream>>>(coors, cursor, sidx);

  point_fused_kernel<<<(NP + 127) / 128, 256, 0, stream>>>(
      x0, w1p, w2p, owp, b1, g1, be1, b2, g2, be2, ob, og, obe, x2, out_pts);

  segmax_kernel<<<NV / 4, 256, 0, stream>>>(x2, offsets, sidx, aggb);

  vox_fused_kernel<<<(NV + 127) / 128, 256, 0, stream>>>(
      aggb, pw1p, pw2p, pb1, pg1, pbe1, pb2, pg2, pbe2, out_vox);
}

// Round 4
// 633.090 us; speedup vs baseline: 1.9355x; 1.2306x over previous
//
#include <hip/hip_runtime.h>

// OnceAggregation R4: sorted-order processing + LDS-resident weights.
//   memset(counts) ; pack_all(+coors+hist) ; scan ; scatter(sidx) ;
//   point_fused (gather features by sidx -> L1 -> L2 -> {x2 seq, out scatter}) ;
//   segmax (sequential stream) ; vox_fused.
// Feature order of x2/agg is permuted by pi (in-register fragment chaining);
// all downstream weight packs compensate. All GEMMs: swapped-operand MFMA
// (y^T = W^T x^T), weights for the point pipeline staged in 112KB LDS.

typedef __attribute__((ext_vector_type(4))) float f32x4;
typedef __attribute__((ext_vector_type(8))) short s16x8;
typedef __attribute__((ext_vector_type(4))) unsigned short u16x4;
typedef __attribute__((ext_vector_type(4))) unsigned int u32x4;

static constexpr int NP = 500000;
static constexpr int NV = 60000;

__device__ __forceinline__ unsigned short f2bf(float f){
  unsigned int u = __float_as_uint(f);
  u = (u + 0x7FFFu + ((u >> 16) & 1u)) >> 16;   // RNE
  return (unsigned short)u;
}

__device__ __forceinline__ unsigned int cvtpk(float lo, float hi){
  unsigned int r;
  asm("v_cvt_pk_bf16_f32 %0, %1, %2" : "=v"(r) : "v"(lo), "v"(hi));
  return r;
}

// ---------------- pack weights + out_coors + histogram, one launch ----------------
__device__ __forceinline__ void pack_one(const float* __restrict__ w,
                                         unsigned short* __restrict__ dst,
                                         int K, int C, bool perm, int idx){
  int j = idx & 7, l = (idx >> 3) & 63, rest = idx >> 9;
  int kcn = K >> 5;
  int kc = rest % kcn, n = rest / kcn;
  int g = l >> 4, t = l & 15;
  int k = perm ? (kc * 32 + ((j >> 2) << 4) + g * 4 + (j & 3))
               : (kc * 32 + g * 8 + j);
  dst[idx] = f2bf(w[(size_t)k * C + n * 16 + t]);
}

__global__ void pack_hist_kernel(const float* __restrict__ w1, const float* __restrict__ w2,
                                 const float* __restrict__ ow, const float* __restrict__ pw1,
                                 const float* __restrict__ pw2,
                                 unsigned short* __restrict__ w1p, unsigned short* __restrict__ w2p,
                                 unsigned short* __restrict__ owp, unsigned short* __restrict__ pw1p,
                                 unsigned short* __restrict__ pw2p,
                                 float* __restrict__ out_coors,
                                 const int* __restrict__ coors, int* __restrict__ counts){
  int stride = gridDim.x * blockDim.x;
  const int T = 196608 + NV + NP;
  for (int i = blockIdx.x * blockDim.x + threadIdx.x; i < T; i += stride){
    if      (i < 16384)       pack_one(w1,  w1p,  128, 128, false, i);
    else if (i < 49152)       pack_one(w2,  w2p,  128, 256, true,  i - 16384);
    else if (i < 65536)       pack_one(ow,  owp,  256, 64,  true,  i - 49152);
    else if (i < 131072)      pack_one(pw1, pw1p, 256, 256, true,  i - 65536);
    else if (i < 196608)      pack_one(pw2, pw2p, 256, 256, true,  i - 131072);
    else if (i < 196608 + NV) out_coors[i - 196608] = (float)(i - 196608);
    else                      atomicAdd(&counts[coors[i - 196608 - NV]], 1);
  }
}

// ---------------- counting sort (scan + scatter) ----------------
__global__ __launch_bounds__(1024)
void scan_kernel(const int* __restrict__ counts, int* __restrict__ offsets,
                 int* __restrict__ cursor){
  __shared__ int part[1024];
  const int t = threadIdx.x;
  constexpr int PER = (NV + 1023) / 1024;
  int base = t * PER;
  int s = 0;
  for (int i = 0; i < PER; ++i){ int b = base + i; if (b < NV) s += counts[b]; }
  part[t] = s;
  __syncthreads();
  for (int d = 1; d < 1024; d <<= 1){
    int u = (t >= d) ? part[t - d] : 0;
    __syncthreads();
    part[t] += u;
    __syncthreads();
  }
  int run = (t > 0) ? part[t - 1] : 0;
  for (int i = 0; i < PER; ++i){
    int b = base + i;
    if (b < NV){ offsets[b] = run; cursor[b] = run; run += counts[b]; }
  }
  if (t == 1023) offsets[NV] = run;
}

__global__ void scatter_kernel(const int* __restrict__ coors, int* __restrict__ cursor,
                               int* __restrict__ sorted_idx){
  int stride = gridDim.x * blockDim.x;
  for (int i = blockIdx.x * blockDim.x + threadIdx.x; i < NP; i += stride){
    int v = coors[i];
    int p = atomicAdd(&cursor[v], 1);
    sorted_idx[p] = i;
  }
}

// sequential segment-max over sorted x2 rows (u16 max exact for relu'd bf16 >= 0)
__global__ __launch_bounds__(256)
void segmax_kernel(const unsigned short* __restrict__ x2, const int* __restrict__ offsets,
                   unsigned short* __restrict__ agg){
  int wid = blockIdx.x * 4 + (threadIdx.x >> 6);
  int lane = threadIdx.x & 63;
  if (wid >= NV) return;
  int beg = offsets[wid], end = offsets[wid + 1];
  const unsigned short* p = x2 + (size_t)beg * 256 + lane * 4;
  u16x4 M0 = {0, 0, 0, 0}, M1 = {0, 0, 0, 0};
  int n = end - beg, i = 0;
  for (; i + 2 <= n; i += 2){
    u16x4 a = *(const u16x4*)p;
    u16x4 b = *(const u16x4*)(p + 256);
    p += 512;
#pragma unroll
    for (int j = 0; j < 4; ++j){ M0[j] = max(M0[j], a[j]); M1[j] = max(M1[j], b[j]); }
  }
  if (i < n){
    u16x4 a = *(const u16x4*)p;
#pragma unroll
    for (int j = 0; j < 4; ++j) M0[j] = max(M0[j], a[j]);
  }
#pragma unroll
  for (int j = 0; j < 4; ++j) M0[j] = max(M0[j], M1[j]);
  *(u16x4*)(agg + (size_t)wid * 256 + lane * 4) = M0;
}

// ---------------- swapped-GEMM building blocks ----------------
template<int KC, int NT>
__device__ __forceinline__ void gemm2x(const s16x8* bA, const s16x8* bB,
                                       const unsigned short* Wp,
                                       int lane, f32x4* dA, f32x4* dB){
#pragma unroll
  for (int n = 0; n < NT; ++n){
    f32x4 aA = {0.f,0.f,0.f,0.f}, aB = {0.f,0.f,0.f,0.f};
#pragma unroll
    for (int kc = 0; kc < KC; ++kc){
      s16x8 w = *(const s16x8*)(Wp + ((n * KC + kc) * 64 + lane) * 8);
      aA = __builtin_amdgcn_mfma_f32_16x16x32_bf16(w, bA[kc], aA, 0, 0, 0);
      aB = __builtin_amdgcn_mfma_f32_16x16x32_bf16(w, bB[kc], aB, 0, 0, 0);
    }
    dA[n] = aA; dB[n] = aB;
  }
}

template<int NT, int C>
__device__ __forceinline__ void bias_ln_relu_sw(f32x4* d0, f32x4* d1,
                                                const float* __restrict__ bias,
                                                const float* __restrict__ gam,
                                                const float* __restrict__ bet, int g){
  float s0 = 0.f, s1 = 0.f, q0 = 0.f, q1 = 0.f;
#pragma unroll
  for (int n = 0; n < NT; ++n){
    f32x4 bv = *(const f32x4*)(bias + n * 16 + g * 4);
#pragma unroll
    for (int i = 0; i < 4; ++i){
      float v0 = d0[n][i] + bv[i]; d0[n][i] = v0; s0 += v0; q0 += v0 * v0;
      float v1 = d1[n][i] + bv[i]; d1[n][i] = v1; s1 += v1; q1 += v1 * v1;
    }
  }
  s0 += __shfl_xor(s0, 16); s0 += __shfl_xor(s0, 32);
  q0 += __shfl_xor(q0, 16); q0 += __shfl_xor(q0, 32);
  s1 += __shfl_xor(s1, 16); s1 += __shfl_xor(s1, 32);
  q1 += __shfl_xor(q1, 16); q1 += __shfl_xor(q1, 32);
  float m0 = s0 * (1.f / C), m1 = s1 * (1.f / C);
  float r0 = rsqrtf(q0 * (1.f / C) - m0 * m0 + 1e-3f);
  float r1 = rsqrtf(q1 * (1.f / C) - m1 * m1 + 1e-3f);
#pragma unroll
  for (int n = 0; n < NT; ++n){
    f32x4 gv  = *(const f32x4*)(gam + n * 16 + g * 4);
    f32x4 bev = *(const f32x4*)(bet + n * 16 + g * 4);
#pragma unroll
    for (int i = 0; i < 4; ++i){
      d0[n][i] = fmaxf((d0[n][i] - m0) * r0 * gv[i] + bev[i], 0.f);
      d1[n][i] = fmaxf((d1[n][i] - m1) * r1 * gv[i] + bev[i], 0.f);
    }
  }
}

// next-layer B frag[kc] = bf16{d[2kc][0..3], d[2kc+1][0..3]} (pi-permuted packs)
template<int NT>
__device__ __forceinline__ void to_frags(const f32x4* d, s16x8* f){
#pragma unroll
  for (int kc = 0; kc < NT / 2; ++kc){
    u32x4 t;
    t[0] = cvtpk(d[2*kc][0],   d[2*kc][1]);
    t[1] = cvtpk(d[2*kc][2],   d[2*kc][3]);
    t[2] = cvtpk(d[2*kc+1][0], d[2*kc+1][1]);
    t[3] = cvtpk(d[2*kc+1][2], d[2*kc+1][3]);
    f[kc] = __builtin_bit_cast(s16x8, t);
  }
}

// gathered x-row fragment load: lane (g) holds cols q*8..q*8+7, q = kc*4+g
__device__ __forceinline__ void load_x(const float* __restrict__ feats,
                                       const float* __restrict__ fclus,
                                       int orig, int g, s16x8* bf){
  const float* rp = feats + (size_t)orig * 125;
#pragma unroll
  for (int kc = 0; kc < 4; ++kc){
    float v[8];
    if (kc < 3 || g < 3){
      int q = kc * 4 + g;
      f32x4 u0 = *(const f32x4*)(rp + q * 8);
      f32x4 u1 = *(const f32x4*)(rp + q * 8 + 4);
#pragma unroll
      for (int i = 0; i < 4; ++i){ v[i] = u0[i]; v[4 + i] = u1[i]; }
    } else {
      f32x4 u0 = *(const f32x4*)(rp + 120);
      const float* fc = fclus + (size_t)orig * 3;
#pragma unroll
      for (int i = 0; i < 4; ++i) v[i] = u0[i];
      v[4] = rp[124];
      v[5] = fc[0] * 0.05f; v[6] = fc[1] * 0.05f; v[7] = fc[2] * 0.25f;
    }
    u32x4 t;
    t[0] = cvtpk(v[0], v[1]); t[1] = cvtpk(v[2], v[3]);
    t[2] = cvtpk(v[4], v[5]); t[3] = cvtpk(v[6], v[7]);
    bf[kc] = __builtin_bit_cast(s16x8, t);
  }
}

// ---------------- fused point pipeline (persistent, weights in LDS) ----------------
__global__ __launch_bounds__(512, 2)
void point_fused_kernel(const float* __restrict__ feats, const float* __restrict__ fclus,
                        const int* __restrict__ sidx,
                        const unsigned short* __restrict__ w1p,
                        const unsigned short* __restrict__ w2p,
                        const unsigned short* __restrict__ owp,
                        const float* __restrict__ b1, const float* __restrict__ g1,
                        const float* __restrict__ be1,
                        const float* __restrict__ b2, const float* __restrict__ g2,
                        const float* __restrict__ be2,
                        const float* __restrict__ ob, const float* __restrict__ og,
                        const float* __restrict__ obe,
                        unsigned short* __restrict__ x2,
                        float* __restrict__ out_pts){
  __shared__ __align__(16) unsigned short wlds[57344];   // 112 KB
  {
    s16x8* dd = (s16x8*)wlds;
    const int tt = threadIdx.x;
    for (int i = tt; i < 2048; i += 512) dd[i]        = ((const s16x8*)w1p)[i];
    for (int i = tt; i < 4096; i += 512) dd[2048 + i] = ((const s16x8*)w2p)[i];
    for (int i = tt; i < 1024; i += 512) dd[6144 + i] = ((const s16x8*)owp)[i];
  }
  __syncthreads();
  const unsigned short* wl1 = wlds;
  const unsigned short* wl2 = wlds + 16384;
  const unsigned short* wlo = wlds + 49152;

  const int lane = threadIdx.x & 63;
  const int wave = threadIdx.x >> 6;
  const int g = lane >> 4, t = lane & 15;
  const int ntiles = (NP + 255) / 256;

  for (int tile = blockIdx.x; tile < ntiles; tile += gridDim.x){
    const int m0 = tile * 256 + wave * 32;
    const int slotA = m0 + t, slotB = m0 + 16 + t;
    const bool okA = slotA < NP, okB = slotB < NP;
    const int origA = sidx[okA ? slotA : 0];
    const int origB = sidx[okB ? slotB : 0];

    s16x8 bfA[4], bfB[4];
    load_x(feats, fclus, origA, g, bfA);
    load_x(feats, fclus, origB, g, bfB);

    f32x4 d1a[8], d1b[8];
    gemm2x<4, 8>(bfA, bfB, wl1, lane, d1a, d1b);
    bias_ln_relu_sw<8, 128>(d1a, d1b, b1, g1, be1, g);

    s16x8 f2a[4], f2b[4];
    to_frags<8>(d1a, f2a); to_frags<8>(d1b, f2b);

    f32x4 d2a[16], d2b[16];
    gemm2x<4, 16>(f2a, f2b, wl2, lane, d2a, d2b);
    bias_ln_relu_sw<16, 256>(d2a, d2b, b2, g2, be2, g);

    s16x8 f3a[8], f3b[8];
    to_frags<16>(d2a, f3a); to_frags<16>(d2b, f3b);

#pragma unroll
    for (int kc = 0; kc < 8; ++kc){
      if (okA) *(s16x8*)(x2 + (size_t)slotA * 256 + kc * 32 + g * 8) = f3a[kc];
      if (okB) *(s16x8*)(x2 + (size_t)slotB * 256 + kc * 32 + g * 8) = f3b[kc];
    }

    f32x4 d3a[4], d3b[4];
    gemm2x<8, 4>(f3a, f3b, wlo, lane, d3a, d3b);
    bias_ln_relu_sw<4, 64>(d3a, d3b, ob, og, obe, g);
#pragma unroll
    for (int n = 0; n < 4; ++n){
      if (okA) *(f32x4*)(out_pts + (size_t)origA * 64 + n * 16 + g * 4) = d3a[n];
      if (okB) *(f32x4*)(out_pts + (size_t)origB * 64 + n * 16 + g * 4) = d3b[n];
    }
  }
}

// ---------------- fused voxel pipeline ----------------
__global__ __launch_bounds__(256, 2)
void vox_fused_kernel(const unsigned short* __restrict__ agg,
                      const unsigned short* __restrict__ pw1p,
                      const unsigned short* __restrict__ pw2p,
                      const float* __restrict__ pb1, const float* __restrict__ pg1,
                      const float* __restrict__ pbe1,
                      const float* __restrict__ pb2, const float* __restrict__ pg2,
                      const float* __restrict__ pbe2,
                      float* __restrict__ out_vox){
  const int lane = threadIdx.x & 63;
  const int wave = threadIdx.x >> 6;
  const int m0 = blockIdx.x * 128 + wave * 32;
  if (m0 >= NV) return;
  const int g = lane >> 4, t = lane & 15;
  const size_t mA = m0 + t, mB = m0 + 16 + t;

  s16x8 bfA[8], bfB[8];
#pragma unroll
  for (int kc = 0; kc < 8; ++kc){
    bfA[kc] = *(const s16x8*)(agg + mA * 256 + kc * 32 + g * 8);
    bfB[kc] = *(const s16x8*)(agg + mB * 256 + kc * 32 + g * 8);
  }
  f32x4 da[16], db[16];
  gemm2x<8, 16>(bfA, bfB, pw1p, lane, da, db);
  bias_ln_relu_sw<16, 256>(da, db, pb1, pg1, pbe1, g);

  s16x8 fa[8], fb[8];
  to_frags<16>(da, fa); to_frags<16>(db, fb);

  gemm2x<8, 16>(fa, fb, pw2p, lane, da, db);
  bias_ln_relu_sw<16, 256>(da, db, pb2, pg2, pbe2, g);
#pragma unroll
  for (int n = 0; n < 16; ++n){
    *(f32x4*)(out_vox + mA * 256 + n * 16 + g * 4) = da[n];
    *(f32x4*)(out_vox + mB * 256 + n * 16 + g * 4) = db[n];
  }
}

extern "C" void kernel_launch(void* const* d_in, const int* in_sizes, int n_in,
                              void* d_out, int out_size, void* d_ws, size_t ws_size,
                              hipStream_t stream){
  const float* features  = (const float*)d_in[1];
  const int*   coors     = (const int*)  d_in[2];
  const float* f_cluster = (const float*)d_in[3];
  const float* w1  = (const float*)d_in[4];
  const float* b1  = (const float*)d_in[5];
  const float* g1  = (const float*)d_in[6];
  const float* be1 = (const float*)d_in[7];
  const float* w2  = (const float*)d_in[8];
  const float* b2  = (const float*)d_in[9];
  const float* g2  = (const float*)d_in[10];
  const float* be2 = (const float*)d_in[11];
  const float* pw1 = (const float*)d_in[12];
  const float* pb1 = (const float*)d_in[13];
  const float* pg1 = (const float*)d_in[14];
  const float* pbe1= (const float*)d_in[15];
  const float* pw2 = (const float*)d_in[16];
  const float* pb2 = (const float*)d_in[17];
  const float* pg2 = (const float*)d_in[18];
  const float* pbe2= (const float*)d_in[19];
  const float* ow  = (const float*)d_in[20];
  const float* ob  = (const float*)d_in[21];
  const float* og  = (const float*)d_in[22];
  const float* obe = (const float*)d_in[23];

  char* ws = (char*)d_ws;
  unsigned short* x2   = (unsigned short*)(ws + 0);              // 256,000,000 B
  unsigned short* aggb = (unsigned short*)(ws + 256000000ull);   // 30,720,000 B
  int* counts   = (int*)(ws + 287000000ull);
  int* offsets  = (int*)(ws + 287250000ull);
  int* cursor   = (int*)(ws + 287500000ull);
  int* sidx     = (int*)(ws + 287750000ull);                     // 2,000,000 B
  unsigned short* w1p = (unsigned short*)(ws + 290000000ull);
  unsigned short* w2p = (unsigned short*)(ws + 290000000ull + 1*262144ull);
  unsigned short* owp = (unsigned short*)(ws + 290000000ull + 2*262144ull);
  unsigned short* pw1p= (unsigned short*)(ws + 290000000ull + 3*262144ull);
  unsigned short* pw2p= (unsigned short*)(ws + 290000000ull + 4*262144ull);

  float* outp      = (float*)d_out;
  float* out_pts   = outp;                       // [N,64]
  float* out_vox   = outp + 32000000;            // [V,256]
  float* out_coors = outp + 47360000;            // [V] as float

  hipMemsetAsync(counts, 0, (size_t)NV * sizeof(int), stream);

  pack_hist_kernel<<<2048, 256, 0, stream>>>(w1, w2, ow, pw1, pw2,
                                             w1p, w2p, owp, pw1p, pw2p,
                                             out_coors, coors, counts);

  scan_kernel<<<1, 1024, 0, stream>>>(counts, offsets, cursor);
  scatter_kernel<<<2048, 256, 0, stream>>>(coors, cursor, sidx);

  point_fused_kernel<<<256, 512, 0, stream>>>(
      features, f_cluster, sidx, w1p, w2p, owp,
      b1, g1, be1, b2, g2, be2, ob, og, obe, x2, out_pts);

  segmax_kernel<<<NV / 4, 256, 0, stream>>>(x2, offsets, aggb);

  vox_fused_kernel<<<(NV + 127) / 128, 256, 0, stream>>>(
      aggb, pw1p, pw2p, pb1, pg1, pbe1, pb2, pg2, pbe2, out_vox);
}